// Round 5
// baseline (286.355 us; speedup 1.0000x reference)
//
#include <hip/hip_runtime.h>
#include <hip/hip_bf16.h>
#include <stdint.h>

// Problem constants: B=64, L=96, C=32, H=256, NL=2, K=3, TAU=2, VTH=1
// n = b*32 + c indexes the B*C=2048 "rows"; layer width H=256.
//
// R20 = VALU-CAPACITY PROBE. R18 base (PAIR interleave + XCD swizzle,
// measured 252.45) + 128 independent v_fmac_f32 per step (inline-asm pinned,
// 4 chains, asm-sunk). Decision math bit-identical.
// Probe ladder so far: MFMA x2 -> +16.9 us (marginal 13.3 cyc/MFMA, pipe has
// slack; rnn <= 103.6 us, enc >= 21 us). This round: VALU x~2.3.
// Committed predictions: VALU-bound +18..22 | issue-bound +9..12 | else +0..4.

using floatx4 = __attribute__((ext_vector_type(4))) float;
using intx4   = __attribute__((ext_vector_type(4))) int;

// ---------------------------------------------------------------------------
// prep: per output-neuron o (256 blocks x 64 threads)  [unchanged]
// ---------------------------------------------------------------------------
__global__ void prep_kernel(const float* __restrict__ w_enc,
                            const float* __restrict__ b_enc,
                            const float* __restrict__ w_rnn,
                            const float* __restrict__ b_rnn,
                            double* __restrict__ Wd,
                            double* __restrict__ C0d,
                            signed char* __restrict__ Bw8)
{
    const int o = blockIdx.x;
    const int lane = threadIdx.x;   // 64 threads
    const float4 w0v = *(const float4*)(w_rnn + (size_t)o * 256 + lane * 4);
    double a0 = 0.0, a1 = 0.0, a2 = 0.0, ab = 0.0;
#pragma unroll
    for (int e = 0; e < 4; ++e) {
        const int i = lane * 4 + e;
        const double wv = (double)(((const float*)&w0v)[e]);
        a0 += wv * (double)w_enc[i * 3 + 0];
        a1 += wv * (double)w_enc[i * 3 + 1];
        a2 += wv * (double)w_enc[i * 3 + 2];
        ab += wv * (double)b_enc[i];
    }
    for (int off = 32; off > 0; off >>= 1) {
        a0 += __shfl_down(a0, off, 64);
        a1 += __shfl_down(a1, off, 64);
        a2 += __shfl_down(a2, off, 64);
        ab += __shfl_down(ab, off, 64);
    }
    if (lane == 0) {
        Wd[o * 3 + 0] = a0;
        Wd[o * 3 + 1] = a1;
        Wd[o * 3 + 2] = a2;
        C0d[o] = ab + (double)b_rnn[o];
    }
    // i8 digit planes of w1 (layer-1), 4 consecutive k per lane
    const float4 w1v = *(const float4*)(w_rnn + 65536 + (size_t)o * 256 + lane * 4);
    unsigned int pack[4] = {0u, 0u, 0u, 0u};   // pack[l]: digits for e=0..3
#pragma unroll
    for (int e = 0; e < 4; ++e) {
        float f = ((const float*)&w1v)[e];
        int q = __double2int_rn((double)f * 134217728.0);   // w * 2^27, |q| <= 2^27
        int d3 = ((q + 64) & 127) - 64;  q = (q - d3) >> 7;
        int d2 = ((q + 64) & 127) - 64;  q = (q - d2) >> 7;
        int d1 = ((q + 64) & 127) - 64;  q = (q - d1) >> 7;
        int d0 = q;                       // |d0| <= 64
        pack[0] |= ((unsigned int)(d0 & 0xFF)) << (8 * e);
        pack[1] |= ((unsigned int)(d1 & 0xFF)) << (8 * e);
        pack[2] |= ((unsigned int)(d2 & 0xFF)) << (8 * e);
        pack[3] |= ((unsigned int)(d3 & 0xFF)) << (8 * e);
    }
#pragma unroll
    for (int l = 0; l < 4; ++l)
        *(unsigned int*)(Bw8 + ((size_t)o * 4 + l) * 256 + lane * 4) = pack[l];
}

// ---------------------------------------------------------------------------
// enc: layer-0 full scan.  [unchanged]
// ---------------------------------------------------------------------------
__global__ void enc_kernel(const float* __restrict__ inputs,
                           const double* __restrict__ Wd,
                           const double* __restrict__ C0d,
                           unsigned char* __restrict__ s0b)
{
    const int n = blockIdx.x;
    const int tidx = threadIdx.x;
    const int b = n >> 5, c = n & 31;
    __shared__ float xr[98];
    if (tidx < 96)       xr[tidx + 1] = inputs[((size_t)b * 96 + tidx) * 32 + c];
    else if (tidx == 96) xr[0]  = 0.0f;
    else if (tidx == 97) xr[97] = 0.0f;
    __syncthreads();
    const double W0 = Wd[tidx * 3], W1 = Wd[tidx * 3 + 1], W2 = Wd[tidx * 3 + 2];
    const double c0 = C0d[tidx];
    const int wid = tidx >> 6, lane = tidx & 63;
    float v = 0.0f;
    for (int t = 0; t < 96; ++t) {
        float cur = (float)((double)xr[t] * W0 + (double)xr[t + 1] * W1 +
                            (double)xr[t + 2] * W2 + c0);
        float vv = v + (cur - v) * 0.5f;
        int sp = (vv - 1.0f) >= 0.0f;
        v = sp ? 0.0f : vv;
        unsigned long long bal = __ballot(sp);
        if ((lane & 15) == 0) {
            const int j = lane >> 4;
            *(unsigned short*)(s0b + ((size_t)t * 2048 + n) * 32 + 8 * j + 2 * wid)
                = (unsigned short)(bal >> (16 * j));
        }
    }
}

// ---------------------------------------------------------------------------
// rnn R20 PROBE: R18 structure + 512 independent v_fmac_f32 per iteration
// (4 chains, inline asm -> exact instruction, no v_pk packing, no DCE).
// Real decision math BIT-IDENTICAL to R18/champion.
// ---------------------------------------------------------------------------
__global__ __launch_bounds__(128, 2) void rnn_kernel(
    const unsigned char* __restrict__ s0b,
    const signed char* __restrict__ Bw8,
    const float* __restrict__ b_rnn,
    float* __restrict__ out0,
    float* __restrict__ out1)
{
    const int tid  = threadIdx.x;
    const int wid  = tid >> 6, lane = tid & 63;
    const int m    = lane & 15, g = lane >> 4;

    // --- XCD-aware job mapping (bijective) [as R18]
    const int bidx = blockIdx.x;            // 0..1023
    const int xcd  = bidx & 7;
    const int u    = bidx >> 3;             // 0..127
    const int rt   = 16 * xcd + (u & 15);   // 128 row-tiles
    const int cp   = u >> 4;                // 0..7 col-pairs
    const int ct   = cp * 2 + wid;          // 16 col-tiles
    const int nw   = rt * 16;
    const int o0   = ct * 16;

    // --- weight A-fragments (loop-invariant): 4 limbs x 4 chunks = 64 VGPRs
    intx4 bfrag[4][4];
#pragma unroll
    for (int l = 0; l < 4; ++l)
#pragma unroll
        for (int c = 0; c < 4; ++c)
            bfrag[l][c] = *(const intx4*)(Bw8 + ((size_t)(o0 + m) * 4 + l) * 256
                                               + c * 64 + g * 16);
    // per-lane bias for out-cols o0+4g .. o0+4g+3
    const float4 biasv = *(const float4*)(b_rnn + 256 + o0 + g * 4);

    // --- store base: spike-row nw+m, col o0+4g (16B-aligned) ---
    float* pb = out0 + ((size_t)(nw >> 5) * 96) * 8192
                     + (size_t)((nw & 31) + m) * 256 + o0 + g * 4;

    // --- mask stream: lane reads uint2 at row*32 + 8g ---
    const unsigned char* mp = s0b + ((size_t)(nw + m)) * 32 + 8 * g;

    floatx4 v = {0.f, 0.f, 0.f, 0.f};

    // PROBE state: 4 independent fmac chains + pinned const operands
    float q0 = v[0] + 0.25f, q1 = v[1] + 0.50f;
    float q2 = v[2] + 0.75f, q3 = v[3] + 1.25f;
    const float kA = 1.0000001f;
    const float kB = 0.0000001f;

    // 256 v_fmac_f32: 64 x 4 independent chains (dep depth 4cyc, ILP 4)
    #define DUMMY_VALU256()                                                    \
    do {                                                                       \
        _Pragma("unroll")                                                      \
        for (int qq = 0; qq < 64; ++qq) {                                      \
            asm("v_fmac_f32 %0, %1, %2" : "+v"(q0) : "v"(kA), "v"(kB));        \
            asm("v_fmac_f32 %0, %1, %2" : "+v"(q1) : "v"(kA), "v"(kB));        \
            asm("v_fmac_f32 %0, %1, %2" : "+v"(q2) : "v"(kA), "v"(kB));        \
            asm("v_fmac_f32 %0, %1, %2" : "+v"(q3) : "v"(kA), "v"(kB));        \
        }                                                                      \
    } while (0)

    // Two steps' MFMAs interleaved at chunk level: 8 independent chains.
    #define PAIR_MFMA(MX, MY, XA0, XA1, XA2, XA3, YA0, YA1, YA2, YA3)          \
    do {                                                                       \
        unsigned int hwx_[4] = { (MX).x & 0xFFFFu, (MX).x >> 16,               \
                                 (MX).y & 0xFFFFu, (MX).y >> 16 };             \
        unsigned int hwy_[4] = { (MY).x & 0xFFFFu, (MY).x >> 16,               \
                                 (MY).y & 0xFFFFu, (MY).y >> 16 };             \
        _Pragma("unroll")                                                      \
        for (int c = 0; c < 4; ++c) {                                          \
            unsigned int hx_ = hwx_[c], hy_ = hwy_[c];                         \
            intx4 ax_, ay_;                                                    \
            ax_.x = (int)(__umul24( hx_        & 0xFu, 0x00204081u) & 0x01010101u); \
            ax_.y = (int)(__umul24((hx_ >> 4)  & 0xFu, 0x00204081u) & 0x01010101u); \
            ax_.z = (int)(__umul24((hx_ >> 8)  & 0xFu, 0x00204081u) & 0x01010101u); \
            ax_.w = (int)(__umul24((hx_ >> 12) & 0xFu, 0x00204081u) & 0x01010101u); \
            XA0 = __builtin_amdgcn_mfma_i32_16x16x64_i8(bfrag[0][c], ax_, XA0, 0, 0, 0); \
            XA1 = __builtin_amdgcn_mfma_i32_16x16x64_i8(bfrag[1][c], ax_, XA1, 0, 0, 0); \
            XA2 = __builtin_amdgcn_mfma_i32_16x16x64_i8(bfrag[2][c], ax_, XA2, 0, 0, 0); \
            XA3 = __builtin_amdgcn_mfma_i32_16x16x64_i8(bfrag[3][c], ax_, XA3, 0, 0, 0); \
            ay_.x = (int)(__umul24( hy_        & 0xFu, 0x00204081u) & 0x01010101u); \
            ay_.y = (int)(__umul24((hy_ >> 4)  & 0xFu, 0x00204081u) & 0x01010101u); \
            ay_.z = (int)(__umul24((hy_ >> 8)  & 0xFu, 0x00204081u) & 0x01010101u); \
            ay_.w = (int)(__umul24((hy_ >> 12) & 0xFu, 0x00204081u) & 0x01010101u); \
            YA0 = __builtin_amdgcn_mfma_i32_16x16x64_i8(bfrag[0][c], ay_, YA0, 0, 0, 0); \
            YA1 = __builtin_amdgcn_mfma_i32_16x16x64_i8(bfrag[1][c], ay_, YA1, 0, 0, 0); \
            YA2 = __builtin_amdgcn_mfma_i32_16x16x64_i8(bfrag[2][c], ay_, YA2, 0, 0, 0); \
            YA3 = __builtin_amdgcn_mfma_i32_16x16x64_i8(bfrag[3][c], ay_, YA3, 0, 0, 0); \
        }                                                                      \
    } while (0)

    #define MEMBRANE(ACC0, ACC1, ACC2, ACC3, SV)                               \
    do {                                                                       \
        _Pragma("unroll")                                                      \
        for (int r = 0; r < 4; ++r) {                                          \
            int a01 = (ACC0)[r] * 128 + (ACC1)[r];   /* exact, |.| < 2^22 */   \
            int a23 = (ACC2)[r] * 128 + (ACC3)[r];                             \
            float cur = fmaf((float)a01, 0x1p-13f, (float)a23 * 0x1p-27f)      \
                        + ((const float*)&biasv)[r];                           \
            float vv = v[r];                                                   \
            vv = vv + (cur - vv) * 0.5f;                                       \
            float s = ((vv - 1.0f) >= 0.0f) ? 1.0f : 0.0f;                     \
            v[r] = vv * (1.0f - s);                                            \
            (SV)[r] = s;                                                       \
        }                                                                      \
    } while (0)

    // ---- pipeline state: group-A accumulators (persist across iterations) --
    intx4 A00 = {0,0,0,0}, A01 = {0,0,0,0}, A02 = {0,0,0,0}, A03 = {0,0,0,0};
    intx4 A10 = {0,0,0,0}, A11 = {0,0,0,0}, A12 = {0,0,0,0}, A13 = {0,0,0,0};

    // prologue: masks for steps 0..3, issue group 0 (steps 0,1) MFMAs
    uint2 mA0 = *(const uint2*)(mp);
    uint2 mA1 = *(const uint2*)(mp + 65536);
    uint2 mB0 = *(const uint2*)(mp + 2 * 65536);
    uint2 mB1 = *(const uint2*)(mp + 3 * 65536);
    PAIR_MFMA(mA0, mA1, A00, A01, A02, A03, A10, A11, A12, A13);

    // main loop: t = 0,4,...,88 (23 iterations, 4 steps each)
    for (int t = 0; t < 92; t += 4) {
        uint2 mC0 = *(const uint2*)(mp + (size_t)(t + 4) * 65536);
        uint2 mC1 = *(const uint2*)(mp + (size_t)(t + 5) * 65536);

        intx4 B00 = {0,0,0,0}, B01 = {0,0,0,0}, B02 = {0,0,0,0}, B03 = {0,0,0,0};
        intx4 B10 = {0,0,0,0}, B11 = {0,0,0,0}, B12 = {0,0,0,0}, B13 = {0,0,0,0};
        PAIR_MFMA(mB0, mB1, B00, B01, B02, B03, B10, B11, B12, B13);

        floatx4 svA0, svA1;
        MEMBRANE(A00, A01, A02, A03, svA0);
        *(floatx4*)pb = svA0;
        MEMBRANE(A10, A11, A12, A13, svA1);
        *(floatx4*)(pb + 8192) = svA1;

        DUMMY_VALU256();   // PROBE: 256 independent v_fmac_f32

        uint2 mD0 = *(const uint2*)(mp + (size_t)(t + 6) * 65536);
        uint2 mD1 = *(const uint2*)(mp + (size_t)(t + 7) * 65536);

        A00 = (intx4){0,0,0,0}; A01 = (intx4){0,0,0,0};
        A02 = (intx4){0,0,0,0}; A03 = (intx4){0,0,0,0};
        A10 = (intx4){0,0,0,0}; A11 = (intx4){0,0,0,0};
        A12 = (intx4){0,0,0,0}; A13 = (intx4){0,0,0,0};
        PAIR_MFMA(mC0, mC1, A00, A01, A02, A03, A10, A11, A12, A13);

        floatx4 svB0, svB1;
        MEMBRANE(B00, B01, B02, B03, svB0);
        *(floatx4*)(pb + 16384) = svB0;
        MEMBRANE(B10, B11, B12, B13, svB1);
        *(floatx4*)(pb + 24576) = svB1;

        DUMMY_VALU256();   // PROBE: 256 independent v_fmac_f32

        pb += 32768;
        mB0 = mD0; mB1 = mD1;
    }

    // epilogue: A holds steps 92,93 (in flight); mB holds masks for 94,95
    {
        intx4 B00 = {0,0,0,0}, B01 = {0,0,0,0}, B02 = {0,0,0,0}, B03 = {0,0,0,0};
        intx4 B10 = {0,0,0,0}, B11 = {0,0,0,0}, B12 = {0,0,0,0}, B13 = {0,0,0,0};
        PAIR_MFMA(mB0, mB1, B00, B01, B02, B03, B10, B11, B12, B13);

        floatx4 svA0, svA1, svB0, svB1;
        MEMBRANE(A00, A01, A02, A03, svA0);
        *(floatx4*)pb = svA0;
        MEMBRANE(A10, A11, A12, A13, svA1);
        *(floatx4*)(pb + 8192) = svA1;
        MEMBRANE(B00, B01, B02, B03, svB0);
        *(floatx4*)(pb + 16384) = svB0;
        MEMBRANE(B10, B11, B12, B13, svB1);
        *(floatx4*)(pb + 24576) = svB1;
        *(floatx4*)(out1 + (size_t)(nw + m) * 256 + o0 + g * 4) = svB1;
    }

    // PROBE: keep fmac chains live
    asm volatile("" :: "v"(q0), "v"(q1), "v"(q2), "v"(q3));

    #undef PAIR_MFMA
    #undef MEMBRANE
    #undef DUMMY_VALU256
}

// ---------------------------------------------------------------------------
extern "C" void kernel_launch(void* const* d_in, const int* in_sizes, int n_in,
                              void* d_out, int out_size, void* d_ws, size_t ws_size,
                              hipStream_t stream) {
    const float* inputs = (const float*)d_in[0];   // [64,96,32]
    const float* w_enc  = (const float*)d_in[1];   // [256,1,3]
    const float* b_enc  = (const float*)d_in[2];   // [256]
    const float* w_rnn  = (const float*)d_in[3];   // [2,256,256]
    const float* b_rnn  = (const float*)d_in[4];   // [2,256]

    float* out0 = (float*)d_out;                       // [64,96,8192]
    float* out1 = out0 + (size_t)64 * 96 * 8192;       // [64,8192]

    char* ws = (char*)d_ws;
    double*      Wd  = (double*)(ws);                  //  768 doubles  [0,6144)
    double*      C0d = (double*)(ws + 6144);           //  256 doubles  [6144,8192)
    signed char* Bw8 = (signed char*)(ws + 8192);      //  256*4*256 i8 [8192,270336)
    unsigned char* s0b = (unsigned char*)(ws + 270336);// 98*65536 B spike bits (2 pad slots)

    prep_kernel<<<256, 64, 0, stream>>>(w_enc, b_enc, w_rnn, b_rnn, Wd, C0d, Bw8);
    enc_kernel<<<2048, 256, 0, stream>>>(inputs, Wd, C0d, s0b);
    rnn_kernel<<<1024, 128, 0, stream>>>(s0b, Bw8, b_rnn, out0, out1);
}

// Round 6
// 252.328 us; speedup vs baseline: 1.1349x; 1.1349x over previous
//
#include <hip/hip_runtime.h>
#include <hip/hip_bf16.h>
#include <stdint.h>

// Problem constants: B=64, L=96, C=32, H=256, NL=2, K=3, TAU=2, VTH=1
// n = b*32 + c indexes the B*C=2048 "rows"; layer width H=256.
//
// R21: VALU-cut + phase-stagger. From probes: VALU marginal = full rate
// (pipe saturated), MFMA marginal ~7.6cyc at deflated clock; pipes nearly
// serialized at 2 waves/SIMD (phase-locked same-code waves). Changes:
// ZERO-C (kill 16 v_mov/step), direct bfe nibbles, cndmask reset, and a
// one-time ~320cyc stagger for wid==1 to anti-phase the block's waves.

using floatx4 = __attribute__((ext_vector_type(4))) float;
using intx4   = __attribute__((ext_vector_type(4))) int;

// ---------------------------------------------------------------------------
// prep: per output-neuron o (256 blocks x 64 threads)  [unchanged]
// ---------------------------------------------------------------------------
__global__ void prep_kernel(const float* __restrict__ w_enc,
                            const float* __restrict__ b_enc,
                            const float* __restrict__ w_rnn,
                            const float* __restrict__ b_rnn,
                            double* __restrict__ Wd,
                            double* __restrict__ C0d,
                            signed char* __restrict__ Bw8)
{
    const int o = blockIdx.x;
    const int lane = threadIdx.x;   // 64 threads
    const float4 w0v = *(const float4*)(w_rnn + (size_t)o * 256 + lane * 4);
    double a0 = 0.0, a1 = 0.0, a2 = 0.0, ab = 0.0;
#pragma unroll
    for (int e = 0; e < 4; ++e) {
        const int i = lane * 4 + e;
        const double wv = (double)(((const float*)&w0v)[e]);
        a0 += wv * (double)w_enc[i * 3 + 0];
        a1 += wv * (double)w_enc[i * 3 + 1];
        a2 += wv * (double)w_enc[i * 3 + 2];
        ab += wv * (double)b_enc[i];
    }
    for (int off = 32; off > 0; off >>= 1) {
        a0 += __shfl_down(a0, off, 64);
        a1 += __shfl_down(a1, off, 64);
        a2 += __shfl_down(a2, off, 64);
        ab += __shfl_down(ab, off, 64);
    }
    if (lane == 0) {
        Wd[o * 3 + 0] = a0;
        Wd[o * 3 + 1] = a1;
        Wd[o * 3 + 2] = a2;
        C0d[o] = ab + (double)b_rnn[o];
    }
    // i8 digit planes of w1 (layer-1), 4 consecutive k per lane
    const float4 w1v = *(const float4*)(w_rnn + 65536 + (size_t)o * 256 + lane * 4);
    unsigned int pack[4] = {0u, 0u, 0u, 0u};   // pack[l]: digits for e=0..3
#pragma unroll
    for (int e = 0; e < 4; ++e) {
        float f = ((const float*)&w1v)[e];
        int q = __double2int_rn((double)f * 134217728.0);   // w * 2^27, |q| <= 2^27
        int d3 = ((q + 64) & 127) - 64;  q = (q - d3) >> 7;
        int d2 = ((q + 64) & 127) - 64;  q = (q - d2) >> 7;
        int d1 = ((q + 64) & 127) - 64;  q = (q - d1) >> 7;
        int d0 = q;                       // |d0| <= 64
        pack[0] |= ((unsigned int)(d0 & 0xFF)) << (8 * e);
        pack[1] |= ((unsigned int)(d1 & 0xFF)) << (8 * e);
        pack[2] |= ((unsigned int)(d2 & 0xFF)) << (8 * e);
        pack[3] |= ((unsigned int)(d3 & 0xFF)) << (8 * e);
    }
#pragma unroll
    for (int l = 0; l < 4; ++l)
        *(unsigned int*)(Bw8 + ((size_t)o * 4 + l) * 256 + lane * 4) = pack[l];
}

// ---------------------------------------------------------------------------
// enc: layer-0 full scan.  [unchanged]
// ---------------------------------------------------------------------------
__global__ void enc_kernel(const float* __restrict__ inputs,
                           const double* __restrict__ Wd,
                           const double* __restrict__ C0d,
                           unsigned char* __restrict__ s0b)
{
    const int n = blockIdx.x;
    const int tidx = threadIdx.x;
    const int b = n >> 5, c = n & 31;
    __shared__ float xr[98];
    if (tidx < 96)       xr[tidx + 1] = inputs[((size_t)b * 96 + tidx) * 32 + c];
    else if (tidx == 96) xr[0]  = 0.0f;
    else if (tidx == 97) xr[97] = 0.0f;
    __syncthreads();
    const double W0 = Wd[tidx * 3], W1 = Wd[tidx * 3 + 1], W2 = Wd[tidx * 3 + 2];
    const double c0 = C0d[tidx];
    const int wid = tidx >> 6, lane = tidx & 63;
    float v = 0.0f;
    for (int t = 0; t < 96; ++t) {
        float cur = (float)((double)xr[t] * W0 + (double)xr[t + 1] * W1 +
                            (double)xr[t + 2] * W2 + c0);
        float vv = v + (cur - v) * 0.5f;
        int sp = (vv - 1.0f) >= 0.0f;
        v = sp ? 0.0f : vv;
        unsigned long long bal = __ballot(sp);
        if ((lane & 15) == 0) {
            const int j = lane >> 4;
            *(unsigned short*)(s0b + ((size_t)t * 2048 + n) * 32 + 8 * j + 2 * wid)
                = (unsigned short)(bal >> (16 * j));
        }
    }
}

// ---------------------------------------------------------------------------
// rnn R21: R18 pipeline structure, minus probes, plus:
//  - ZERO-C: chunk-0 MFMA uses a hoisted zero quad as C (no per-step zeroing)
//  - direct bfe nibble extraction (no halfword temporaries)
//  - cndmask hard reset: v = spike ? 0 : vv  (-0.0 vs +0.0 only; absmax 0)
//  - wid==1 one-time ~320cyc stagger to anti-phase the block's two waves
// Decision math BIT-IDENTICAL per step (integer MFMA accumulation exact;
// fp32 limb combine and membrane in exact reference op order).
// ---------------------------------------------------------------------------
__global__ __launch_bounds__(128, 2) void rnn_kernel(
    const unsigned char* __restrict__ s0b,
    const signed char* __restrict__ Bw8,
    const float* __restrict__ b_rnn,
    float* __restrict__ out0,
    float* __restrict__ out1)
{
    const int tid  = threadIdx.x;
    const int wid  = tid >> 6, lane = tid & 63;
    const int m    = lane & 15, g = lane >> 4;

    // --- XCD-aware job mapping (bijective) [as R18]
    const int bidx = blockIdx.x;            // 0..1023
    const int xcd  = bidx & 7;
    const int u    = bidx >> 3;             // 0..127
    const int rt   = 16 * xcd + (u & 15);   // 128 row-tiles
    const int cp   = u >> 4;                // 0..7 col-pairs
    const int ct   = cp * 2 + wid;          // 16 col-tiles
    const int nw   = rt * 16;
    const int o0   = ct * 16;

    // --- weight A-fragments (loop-invariant): 4 limbs x 4 chunks = 64 VGPRs
    intx4 bfrag[4][4];
#pragma unroll
    for (int l = 0; l < 4; ++l)
#pragma unroll
        for (int c = 0; c < 4; ++c)
            bfrag[l][c] = *(const intx4*)(Bw8 + ((size_t)(o0 + m) * 4 + l) * 256
                                               + c * 64 + g * 16);
    // per-lane bias for out-cols o0+4g .. o0+4g+3
    const float4 biasv = *(const float4*)(b_rnn + 256 + o0 + g * 4);

    // --- store base: spike-row nw+m, col o0+4g (16B-aligned) ---
    float* pb = out0 + ((size_t)(nw >> 5) * 96) * 8192
                     + (size_t)((nw & 31) + m) * 256 + o0 + g * 4;

    // --- mask stream: lane reads uint2 at row*32 + 8g ---
    const unsigned char* mp = s0b + ((size_t)(nw + m)) * 32 + 8 * g;

    floatx4 v = {0.f, 0.f, 0.f, 0.f};

    // hoisted zero quad: C operand of every chunk-0 MFMA (kills per-step
    // accumulator zero-init). Pinned via asm so it stays materialized once.
    intx4 zeroq = {0, 0, 0, 0};
    asm volatile("" : "+v"(zeroq));

    // --- phase stagger: wid==1 delays ~320 cyc once, anti-phasing the two
    // waves so one wave's MFMA burst overlaps the other's membrane VALU.
    if (wid == 1) {
        float qa = biasv.x, qb = biasv.y;
        const float kA = 1.0000001f, kB = 0.0000001f;
#pragma unroll
        for (int qq = 0; qq < 80; ++qq) {
            asm("v_fmac_f32 %0, %1, %2" : "+v"(qa) : "v"(kA), "v"(kB));
            asm("v_fmac_f32 %0, %1, %2" : "+v"(qb) : "v"(kA), "v"(kB));
        }
        asm volatile("" :: "v"(qa), "v"(qb));
    }

    // Two steps' MFMAs interleaved at chunk level; chunk 0 uses zeroq as C.
    #define PAIR_MFMA(MX, MY, XA0, XA1, XA2, XA3, YA0, YA1, YA2, YA3)          \
    do {                                                                       \
        _Pragma("unroll")                                                      \
        for (int c = 0; c < 4; ++c) {                                          \
            const unsigned int sx_ = (c < 2) ? (MX).x : (MX).y;                \
            const unsigned int sy_ = (c < 2) ? (MY).x : (MY).y;                \
            const int sh_ = (c & 1) * 16;                                      \
            intx4 ax_, ay_;                                                    \
            ax_.x = (int)(__umul24((sx_ >> (sh_ + 0))  & 0xFu, 0x00204081u) & 0x01010101u); \
            ax_.y = (int)(__umul24((sx_ >> (sh_ + 4))  & 0xFu, 0x00204081u) & 0x01010101u); \
            ax_.z = (int)(__umul24((sx_ >> (sh_ + 8))  & 0xFu, 0x00204081u) & 0x01010101u); \
            ax_.w = (int)(__umul24((sx_ >> (sh_ + 12)) & 0xFu, 0x00204081u) & 0x01010101u); \
            XA0 = __builtin_amdgcn_mfma_i32_16x16x64_i8(bfrag[0][c], ax_, (c == 0) ? zeroq : XA0, 0, 0, 0); \
            XA1 = __builtin_amdgcn_mfma_i32_16x16x64_i8(bfrag[1][c], ax_, (c == 0) ? zeroq : XA1, 0, 0, 0); \
            XA2 = __builtin_amdgcn_mfma_i32_16x16x64_i8(bfrag[2][c], ax_, (c == 0) ? zeroq : XA2, 0, 0, 0); \
            XA3 = __builtin_amdgcn_mfma_i32_16x16x64_i8(bfrag[3][c], ax_, (c == 0) ? zeroq : XA3, 0, 0, 0); \
            ay_.x = (int)(__umul24((sy_ >> (sh_ + 0))  & 0xFu, 0x00204081u) & 0x01010101u); \
            ay_.y = (int)(__umul24((sy_ >> (sh_ + 4))  & 0xFu, 0x00204081u) & 0x01010101u); \
            ay_.z = (int)(__umul24((sy_ >> (sh_ + 8))  & 0xFu, 0x00204081u) & 0x01010101u); \
            ay_.w = (int)(__umul24((sy_ >> (sh_ + 12)) & 0xFu, 0x00204081u) & 0x01010101u); \
            YA0 = __builtin_amdgcn_mfma_i32_16x16x64_i8(bfrag[0][c], ay_, (c == 0) ? zeroq : YA0, 0, 0, 0); \
            YA1 = __builtin_amdgcn_mfma_i32_16x16x64_i8(bfrag[1][c], ay_, (c == 0) ? zeroq : YA1, 0, 0, 0); \
            YA2 = __builtin_amdgcn_mfma_i32_16x16x64_i8(bfrag[2][c], ay_, (c == 0) ? zeroq : YA2, 0, 0, 0); \
            YA3 = __builtin_amdgcn_mfma_i32_16x16x64_i8(bfrag[3][c], ay_, (c == 0) ? zeroq : YA3, 0, 0, 0); \
        }                                                                      \
    } while (0)

    #define MEMBRANE(ACC0, ACC1, ACC2, ACC3, SV)                               \
    do {                                                                       \
        _Pragma("unroll")                                                      \
        for (int r = 0; r < 4; ++r) {                                          \
            int a01 = (ACC0)[r] * 128 + (ACC1)[r];   /* exact, |.| < 2^22 */   \
            int a23 = (ACC2)[r] * 128 + (ACC3)[r];                             \
            float cur = fmaf((float)a01, 0x1p-13f, (float)a23 * 0x1p-27f)      \
                        + ((const float*)&biasv)[r];                           \
            float vv = v[r];                                                   \
            vv = vv + (cur - vv) * 0.5f;                                       \
            bool  sp = (vv - 1.0f) >= 0.0f;                                    \
            (SV)[r] = sp ? 1.0f : 0.0f;                                        \
            v[r]    = sp ? 0.0f : vv;   /* == vv*(1-s) up to -0 vs +0 */       \
        }                                                                      \
    } while (0)

    // ---- pipeline state: group-A accumulators (persist across iterations) --
    intx4 A00, A01, A02, A03, A10, A11, A12, A13;

    // prologue: masks for steps 0..3, issue group 0 (steps 0,1) MFMAs
    uint2 mA0 = *(const uint2*)(mp);
    uint2 mA1 = *(const uint2*)(mp + 65536);
    uint2 mB0 = *(const uint2*)(mp + 2 * 65536);
    uint2 mB1 = *(const uint2*)(mp + 3 * 65536);
    PAIR_MFMA(mA0, mA1, A00, A01, A02, A03, A10, A11, A12, A13);

    // main loop: t = 0,4,...,88 (23 iterations, 4 steps each)
    for (int t = 0; t < 92; t += 4) {
        uint2 mC0 = *(const uint2*)(mp + (size_t)(t + 4) * 65536);
        uint2 mC1 = *(const uint2*)(mp + (size_t)(t + 5) * 65536);

        // issue group B (steps t+2, t+3) MFMAs — overlap with A's membrane
        intx4 B00, B01, B02, B03, B10, B11, B12, B13;
        PAIR_MFMA(mB0, mB1, B00, B01, B02, B03, B10, B11, B12, B13);

        // membrane + store group A (steps t, t+1) while B MFMAs in flight
        floatx4 svA0, svA1;
        MEMBRANE(A00, A01, A02, A03, svA0);
        *(floatx4*)pb = svA0;
        MEMBRANE(A10, A11, A12, A13, svA1);
        *(floatx4*)(pb + 8192) = svA1;

        uint2 mD0 = *(const uint2*)(mp + (size_t)(t + 6) * 65536);
        uint2 mD1 = *(const uint2*)(mp + (size_t)(t + 7) * 65536);

        // issue next group A (steps t+4, t+5) MFMAs — overlap with B's membrane
        PAIR_MFMA(mC0, mC1, A00, A01, A02, A03, A10, A11, A12, A13);

        // membrane + store group B (steps t+2, t+3)
        floatx4 svB0, svB1;
        MEMBRANE(B00, B01, B02, B03, svB0);
        *(floatx4*)(pb + 16384) = svB0;
        MEMBRANE(B10, B11, B12, B13, svB1);
        *(floatx4*)(pb + 24576) = svB1;

        pb += 32768;
        mB0 = mD0; mB1 = mD1;
    }

    // epilogue: A holds steps 92,93 (in flight); mB holds masks for 94,95
    {
        intx4 B00, B01, B02, B03, B10, B11, B12, B13;
        PAIR_MFMA(mB0, mB1, B00, B01, B02, B03, B10, B11, B12, B13);

        floatx4 svA0, svA1, svB0, svB1;
        MEMBRANE(A00, A01, A02, A03, svA0);
        *(floatx4*)pb = svA0;
        MEMBRANE(A10, A11, A12, A13, svA1);
        *(floatx4*)(pb + 8192) = svA1;
        MEMBRANE(B00, B01, B02, B03, svB0);
        *(floatx4*)(pb + 16384) = svB0;
        MEMBRANE(B10, B11, B12, B13, svB1);
        *(floatx4*)(pb + 24576) = svB1;
        *(floatx4*)(out1 + (size_t)(nw + m) * 256 + o0 + g * 4) = svB1;
    }
    #undef PAIR_MFMA
    #undef MEMBRANE
}

// ---------------------------------------------------------------------------
extern "C" void kernel_launch(void* const* d_in, const int* in_sizes, int n_in,
                              void* d_out, int out_size, void* d_ws, size_t ws_size,
                              hipStream_t stream) {
    const float* inputs = (const float*)d_in[0];   // [64,96,32]
    const float* w_enc  = (const float*)d_in[1];   // [256,1,3]
    const float* b_enc  = (const float*)d_in[2];   // [256]
    const float* w_rnn  = (const float*)d_in[3];   // [2,256,256]
    const float* b_rnn  = (const float*)d_in[4];   // [2,256]

    float* out0 = (float*)d_out;                       // [64,96,8192]
    float* out1 = out0 + (size_t)64 * 96 * 8192;       // [64,8192]

    char* ws = (char*)d_ws;
    double*      Wd  = (double*)(ws);                  //  768 doubles  [0,6144)
    double*      C0d = (double*)(ws + 6144);           //  256 doubles  [6144,8192)
    signed char* Bw8 = (signed char*)(ws + 8192);      //  256*4*256 i8 [8192,270336)
    unsigned char* s0b = (unsigned char*)(ws + 270336);// 98*65536 B spike bits (2 pad slots)

    prep_kernel<<<256, 64, 0, stream>>>(w_enc, b_enc, w_rnn, b_rnn, Wd, C0d, Bw8);
    enc_kernel<<<2048, 256, 0, stream>>>(inputs, Wd, C0d, s0b);
    rnn_kernel<<<1024, 128, 0, stream>>>(s0b, Bw8, b_rnn, out0, out1);
}

// Round 7
// 251.277 us; speedup vs baseline: 1.1396x; 1.0042x over previous
//
#include <hip/hip_runtime.h>
#include <hip/hip_bf16.h>
#include <stdint.h>

// Problem constants: B=64, L=96, C=32, H=256, NL=2, K=3, TAU=2, VTH=1
// n = b*32 + c indexes the B*C=2048 "rows"; layer width H=256.
//
// R22: DUAL-COLUMN SINGLE-WAVE rnn. 1024 jobs of 16 rows x 32 cols
// (128 row-tiles x 8 col-pairs), one wave per job, 1024 blocks x 64 thr,
// __launch_bounds__(64,1) -> 512-VGPR budget, 1 wave/SIMD.
// Rationale (probe ladder R19-R21): VALU pipe saturated (marginal = full
// rate), MFMA pipe has slack; 16 col-jobs redundantly bit-spread the SAME
// row-block masks. Sharing one spread across 2 col-tiles cuts per-SIMD
// VALU/step ~200 -> ~150 and halves mask fetch traffic. 8 independent MFMA
// chains per step come from 2 cols x 4 limbs. Stores: 2x dwordx4 per step
// covering a full 128-B line per row. Decision math BIT-IDENTICAL.

using floatx4 = __attribute__((ext_vector_type(4))) float;
using intx4   = __attribute__((ext_vector_type(4))) int;

// ---------------------------------------------------------------------------
// prep: per output-neuron o (256 blocks x 64 threads)  [unchanged]
// ---------------------------------------------------------------------------
__global__ void prep_kernel(const float* __restrict__ w_enc,
                            const float* __restrict__ b_enc,
                            const float* __restrict__ w_rnn,
                            const float* __restrict__ b_rnn,
                            double* __restrict__ Wd,
                            double* __restrict__ C0d,
                            signed char* __restrict__ Bw8)
{
    const int o = blockIdx.x;
    const int lane = threadIdx.x;   // 64 threads
    const float4 w0v = *(const float4*)(w_rnn + (size_t)o * 256 + lane * 4);
    double a0 = 0.0, a1 = 0.0, a2 = 0.0, ab = 0.0;
#pragma unroll
    for (int e = 0; e < 4; ++e) {
        const int i = lane * 4 + e;
        const double wv = (double)(((const float*)&w0v)[e]);
        a0 += wv * (double)w_enc[i * 3 + 0];
        a1 += wv * (double)w_enc[i * 3 + 1];
        a2 += wv * (double)w_enc[i * 3 + 2];
        ab += wv * (double)b_enc[i];
    }
    for (int off = 32; off > 0; off >>= 1) {
        a0 += __shfl_down(a0, off, 64);
        a1 += __shfl_down(a1, off, 64);
        a2 += __shfl_down(a2, off, 64);
        ab += __shfl_down(ab, off, 64);
    }
    if (lane == 0) {
        Wd[o * 3 + 0] = a0;
        Wd[o * 3 + 1] = a1;
        Wd[o * 3 + 2] = a2;
        C0d[o] = ab + (double)b_rnn[o];
    }
    // i8 digit planes of w1 (layer-1), 4 consecutive k per lane
    const float4 w1v = *(const float4*)(w_rnn + 65536 + (size_t)o * 256 + lane * 4);
    unsigned int pack[4] = {0u, 0u, 0u, 0u};   // pack[l]: digits for e=0..3
#pragma unroll
    for (int e = 0; e < 4; ++e) {
        float f = ((const float*)&w1v)[e];
        int q = __double2int_rn((double)f * 134217728.0);   // w * 2^27, |q| <= 2^27
        int d3 = ((q + 64) & 127) - 64;  q = (q - d3) >> 7;
        int d2 = ((q + 64) & 127) - 64;  q = (q - d2) >> 7;
        int d1 = ((q + 64) & 127) - 64;  q = (q - d1) >> 7;
        int d0 = q;                       // |d0| <= 64
        pack[0] |= ((unsigned int)(d0 & 0xFF)) << (8 * e);
        pack[1] |= ((unsigned int)(d1 & 0xFF)) << (8 * e);
        pack[2] |= ((unsigned int)(d2 & 0xFF)) << (8 * e);
        pack[3] |= ((unsigned int)(d3 & 0xFF)) << (8 * e);
    }
#pragma unroll
    for (int l = 0; l < 4; ++l)
        *(unsigned int*)(Bw8 + ((size_t)o * 4 + l) * 256 + lane * 4) = pack[l];
}

// ---------------------------------------------------------------------------
// enc: layer-0 full scan.  [unchanged]
// ---------------------------------------------------------------------------
__global__ void enc_kernel(const float* __restrict__ inputs,
                           const double* __restrict__ Wd,
                           const double* __restrict__ C0d,
                           unsigned char* __restrict__ s0b)
{
    const int n = blockIdx.x;
    const int tidx = threadIdx.x;
    const int b = n >> 5, c = n & 31;
    __shared__ float xr[98];
    if (tidx < 96)       xr[tidx + 1] = inputs[((size_t)b * 96 + tidx) * 32 + c];
    else if (tidx == 96) xr[0]  = 0.0f;
    else if (tidx == 97) xr[97] = 0.0f;
    __syncthreads();
    const double W0 = Wd[tidx * 3], W1 = Wd[tidx * 3 + 1], W2 = Wd[tidx * 3 + 2];
    const double c0 = C0d[tidx];
    const int wid = tidx >> 6, lane = tidx & 63;
    float v = 0.0f;
    for (int t = 0; t < 96; ++t) {
        float cur = (float)((double)xr[t] * W0 + (double)xr[t + 1] * W1 +
                            (double)xr[t + 2] * W2 + c0);
        float vv = v + (cur - v) * 0.5f;
        int sp = (vv - 1.0f) >= 0.0f;
        v = sp ? 0.0f : vv;
        unsigned long long bal = __ballot(sp);
        if ((lane & 15) == 0) {
            const int j = lane >> 4;
            *(unsigned short*)(s0b + ((size_t)t * 2048 + n) * 32 + 8 * j + 2 * wid)
                = (unsigned short)(bal >> (16 * j));
        }
    }
}

// ---------------------------------------------------------------------------
// rnn R22: 16x32 tile per wave, 1 wave/block, 1024 blocks.
// Per step: ONE bit-spread feeds TWO col-tiles (8 indep MFMA chains =
// 2 cols x 4 limbs). 3-deep step pipeline (champion structure): MFMAs for
// steps t,t+1,t+2 issued with independent acc sets, membranes+stores follow.
// C/D 16x16: M=(lane>>4)*4+reg -> out-col; N=lane&15 -> spike-row.
// ---------------------------------------------------------------------------
__global__ __launch_bounds__(64, 1) void rnn_kernel(
    const unsigned char* __restrict__ s0b,
    const signed char* __restrict__ Bw8,
    const float* __restrict__ b_rnn,
    float* __restrict__ out0,
    float* __restrict__ out1)
{
    const int lane = threadIdx.x & 63;
    const int m    = lane & 15, g = lane >> 4;

    // --- XCD-aware job mapping (bijective): 1024 jobs
    const int bidx  = blockIdx.x;            // 0..1023
    const int xcd   = bidx & 7;
    const int u     = bidx >> 3;             // 0..127
    const int rt    = 16 * xcd + (u & 15);   // 128 row-tiles
    const int cpair = u >> 4;                // 0..7 col-pairs
    const int nw    = rt * 16;
    const int o0    = cpair * 32;            // 32-col span

    // --- weight A-fragments for both col-tiles: 2 x 4 limbs x 4 chunks = 128 VGPRs
    intx4 bfrag[2][4][4];
#pragma unroll
    for (int d = 0; d < 2; ++d)
#pragma unroll
        for (int l = 0; l < 4; ++l)
#pragma unroll
            for (int c = 0; c < 4; ++c)
                bfrag[d][l][c] = *(const intx4*)(Bw8
                    + ((size_t)(o0 + 16 * d + m) * 4 + l) * 256 + c * 64 + g * 16);

    // per-lane bias for out-cols (o0+16d) + 4g .. +3
    const float4 bias0 = *(const float4*)(b_rnn + 256 + o0 + g * 4);
    const float4 bias1 = *(const float4*)(b_rnn + 256 + o0 + 16 + g * 4);

    // --- store base: spike-row nw+m, col o0+4g; col-tile 1 at +16 floats ---
    float* pb = out0 + ((size_t)(nw >> 5) * 96) * 8192
                     + (size_t)((nw & 31) + m) * 256 + o0 + g * 4;

    // --- mask stream: lane reads uint2 at row*32 + 8g ---
    const unsigned char* mp = s0b + ((size_t)(nw + m)) * 32 + 8 * g;

    floatx4 v0 = {0.f, 0.f, 0.f, 0.f};
    floatx4 v1 = {0.f, 0.f, 0.f, 0.f};

    // one spread per chunk feeds both col-tiles: 8 independent chains.
    #define STEP_MFMA2(MASK, P0, P1, P2, P3, Q0, Q1, Q2, Q3)                   \
    do {                                                                       \
        unsigned int hw_[4] = { (MASK).x & 0xFFFFu, (MASK).x >> 16,            \
                                (MASK).y & 0xFFFFu, (MASK).y >> 16 };          \
        _Pragma("unroll")                                                      \
        for (int c = 0; c < 4; ++c) {                                          \
            unsigned int h_ = hw_[c];                                          \
            intx4 a_;                                                          \
            a_.x = (int)(__umul24( h_        & 0xFu, 0x00204081u) & 0x01010101u); \
            a_.y = (int)(__umul24((h_ >> 4)  & 0xFu, 0x00204081u) & 0x01010101u); \
            a_.z = (int)(__umul24((h_ >> 8)  & 0xFu, 0x00204081u) & 0x01010101u); \
            a_.w = (int)(__umul24((h_ >> 12) & 0xFu, 0x00204081u) & 0x01010101u); \
            P0 = __builtin_amdgcn_mfma_i32_16x16x64_i8(bfrag[0][0][c], a_, P0, 0, 0, 0); \
            P1 = __builtin_amdgcn_mfma_i32_16x16x64_i8(bfrag[0][1][c], a_, P1, 0, 0, 0); \
            P2 = __builtin_amdgcn_mfma_i32_16x16x64_i8(bfrag[0][2][c], a_, P2, 0, 0, 0); \
            P3 = __builtin_amdgcn_mfma_i32_16x16x64_i8(bfrag[0][3][c], a_, P3, 0, 0, 0); \
            Q0 = __builtin_amdgcn_mfma_i32_16x16x64_i8(bfrag[1][0][c], a_, Q0, 0, 0, 0); \
            Q1 = __builtin_amdgcn_mfma_i32_16x16x64_i8(bfrag[1][1][c], a_, Q1, 0, 0, 0); \
            Q2 = __builtin_amdgcn_mfma_i32_16x16x64_i8(bfrag[1][2][c], a_, Q2, 0, 0, 0); \
            Q3 = __builtin_amdgcn_mfma_i32_16x16x64_i8(bfrag[1][3][c], a_, Q3, 0, 0, 0); \
        }                                                                      \
    } while (0)

    #define MEMBRANE(ACC0, ACC1, ACC2, ACC3, VV, BIAS, SV)                     \
    do {                                                                       \
        _Pragma("unroll")                                                      \
        for (int r = 0; r < 4; ++r) {                                          \
            int a01 = (ACC0)[r] * 128 + (ACC1)[r];   /* exact, |.| < 2^22 */   \
            int a23 = (ACC2)[r] * 128 + (ACC3)[r];                             \
            float cur = fmaf((float)a01, 0x1p-13f, (float)a23 * 0x1p-27f)      \
                        + ((const float*)&(BIAS))[r];                          \
            float vv = (VV)[r];                                                \
            vv = vv + (cur - vv) * 0.5f;                                       \
            float s = ((vv - 1.0f) >= 0.0f) ? 1.0f : 0.0f;                     \
            (VV)[r] = vv * (1.0f - s);                                         \
            (SV)[r] = s;                                                       \
        }                                                                      \
    } while (0)

    // membrane + both-column stores for one step's acc set
    #define FINISH_STEP(P0, P1, P2, P3, Q0, Q1, Q2, Q3, PBOFF)                 \
    do {                                                                       \
        floatx4 sv0_, sv1_;                                                    \
        MEMBRANE(P0, P1, P2, P3, v0, bias0, sv0_);                             \
        *(floatx4*)(pb + (PBOFF)) = sv0_;                                      \
        MEMBRANE(Q0, Q1, Q2, Q3, v1, bias1, sv1_);                             \
        *(floatx4*)(pb + (PBOFF) + 16) = sv1_;                                 \
    } while (0)

    // --- mask stream: 3 steps in hand ---
    uint2 m0 = *(const uint2*)(mp);
    uint2 m1 = *(const uint2*)(mp + 65536);
    uint2 m2 = *(const uint2*)(mp + 2 * 65536);

    // groups (0..2)..(90..92); peeled (93..95)
    for (int t = 0; t < 93; t += 3) {
        uint2 p3 = *(const uint2*)(mp + (size_t)(t + 3) * 65536);
        uint2 p4 = *(const uint2*)(mp + (size_t)(t + 4) * 65536);
        uint2 p5 = *(const uint2*)(mp + (size_t)(t + 5) * 65536);

        intx4 aP0 = {0,0,0,0}, aP1 = {0,0,0,0}, aP2 = {0,0,0,0}, aP3 = {0,0,0,0};
        intx4 aQ0 = {0,0,0,0}, aQ1 = {0,0,0,0}, aQ2 = {0,0,0,0}, aQ3 = {0,0,0,0};
        intx4 bP0 = {0,0,0,0}, bP1 = {0,0,0,0}, bP2 = {0,0,0,0}, bP3 = {0,0,0,0};
        intx4 bQ0 = {0,0,0,0}, bQ1 = {0,0,0,0}, bQ2 = {0,0,0,0}, bQ3 = {0,0,0,0};
        intx4 cP0 = {0,0,0,0}, cP1 = {0,0,0,0}, cP2 = {0,0,0,0}, cP3 = {0,0,0,0};
        intx4 cQ0 = {0,0,0,0}, cQ1 = {0,0,0,0}, cQ2 = {0,0,0,0}, cQ3 = {0,0,0,0};
        STEP_MFMA2(m0, aP0, aP1, aP2, aP3, aQ0, aQ1, aQ2, aQ3);   // step t
        STEP_MFMA2(m1, bP0, bP1, bP2, bP3, bQ0, bQ1, bQ2, bQ3);   // step t+1
        STEP_MFMA2(m2, cP0, cP1, cP2, cP3, cQ0, cQ1, cQ2, cQ3);   // step t+2

        FINISH_STEP(aP0, aP1, aP2, aP3, aQ0, aQ1, aQ2, aQ3, 0);
        FINISH_STEP(bP0, bP1, bP2, bP3, bQ0, bQ1, bQ2, bQ3, 8192);
        FINISH_STEP(cP0, cP1, cP2, cP3, cQ0, cQ1, cQ2, cQ3, 16384);

        pb += 24576;
        m0 = p3; m1 = p4; m2 = p5;
    }

    // --- peeled group t = 93, 94, 95 (masks already in m0, m1, m2) ---
    {
        intx4 aP0 = {0,0,0,0}, aP1 = {0,0,0,0}, aP2 = {0,0,0,0}, aP3 = {0,0,0,0};
        intx4 aQ0 = {0,0,0,0}, aQ1 = {0,0,0,0}, aQ2 = {0,0,0,0}, aQ3 = {0,0,0,0};
        intx4 bP0 = {0,0,0,0}, bP1 = {0,0,0,0}, bP2 = {0,0,0,0}, bP3 = {0,0,0,0};
        intx4 bQ0 = {0,0,0,0}, bQ1 = {0,0,0,0}, bQ2 = {0,0,0,0}, bQ3 = {0,0,0,0};
        intx4 cP0 = {0,0,0,0}, cP1 = {0,0,0,0}, cP2 = {0,0,0,0}, cP3 = {0,0,0,0};
        intx4 cQ0 = {0,0,0,0}, cQ1 = {0,0,0,0}, cQ2 = {0,0,0,0}, cQ3 = {0,0,0,0};
        STEP_MFMA2(m0, aP0, aP1, aP2, aP3, aQ0, aQ1, aQ2, aQ3);
        STEP_MFMA2(m1, bP0, bP1, bP2, bP3, bQ0, bQ1, bQ2, bQ3);
        STEP_MFMA2(m2, cP0, cP1, cP2, cP3, cQ0, cQ1, cQ2, cQ3);

        FINISH_STEP(aP0, aP1, aP2, aP3, aQ0, aQ1, aQ2, aQ3, 0);
        FINISH_STEP(bP0, bP1, bP2, bP3, bQ0, bQ1, bQ2, bQ3, 8192);

        floatx4 sv0_, sv1_;
        MEMBRANE(cP0, cP1, cP2, cP3, v0, bias0, sv0_);
        *(floatx4*)(pb + 16384) = sv0_;
        MEMBRANE(cQ0, cQ1, cQ2, cQ3, v1, bias1, sv1_);
        *(floatx4*)(pb + 16384 + 16) = sv1_;

        float* p1 = out1 + (size_t)(nw + m) * 256 + o0 + g * 4;
        *(floatx4*)p1        = sv0_;
        *(floatx4*)(p1 + 16) = sv1_;
    }
    #undef STEP_MFMA2
    #undef MEMBRANE
    #undef FINISH_STEP
}

// ---------------------------------------------------------------------------
extern "C" void kernel_launch(void* const* d_in, const int* in_sizes, int n_in,
                              void* d_out, int out_size, void* d_ws, size_t ws_size,
                              hipStream_t stream) {
    const float* inputs = (const float*)d_in[0];   // [64,96,32]
    const float* w_enc  = (const float*)d_in[1];   // [256,1,3]
    const float* b_enc  = (const float*)d_in[2];   // [256]
    const float* w_rnn  = (const float*)d_in[3];   // [2,256,256]
    const float* b_rnn  = (const float*)d_in[4];   // [2,256]

    float* out0 = (float*)d_out;                       // [64,96,8192]
    float* out1 = out0 + (size_t)64 * 96 * 8192;       // [64,8192]

    char* ws = (char*)d_ws;
    double*      Wd  = (double*)(ws);                  //  768 doubles  [0,6144)
    double*      C0d = (double*)(ws + 6144);           //  256 doubles  [6144,8192)
    signed char* Bw8 = (signed char*)(ws + 8192);      //  256*4*256 i8 [8192,270336)
    unsigned char* s0b = (unsigned char*)(ws + 270336);// 98*65536 B spike bits (2 pad slots)

    prep_kernel<<<256, 64, 0, stream>>>(w_enc, b_enc, w_rnn, b_rnn, Wd, C0d, Bw8);
    enc_kernel<<<2048, 256, 0, stream>>>(inputs, Wd, C0d, s0b);
    rnn_kernel<<<1024, 64, 0, stream>>>(s0b, Bw8, b_rnn, out0, out1);
}

// Round 8
// 247.656 us; speedup vs baseline: 1.1563x; 1.0146x over previous
//
#include <hip/hip_runtime.h>
#include <hip/hip_bf16.h>
#include <stdint.h>

// Problem constants: B=64, L=96, C=32, H=256, NL=2, K=3, TAU=2, VTH=1
// n = b*32 + c indexes the B*C=2048 "rows"; layer width H=256.
//
// R23: enc LDS-batched coalesced stores. Timing model (validated by probe
// ladder R19/R20): dur = fixed 123us harness fill + prep + enc + rnn.
// enc >= 21us with 3.1M scattered 2-B stores -> batch 8 timesteps in a
// 256-B LDS tile, flush as 16-B dwordx4 (8x fewer, coalesced). Math and
// output bytes bit-identical. rnn = R22 dual-column single-wave (best,
// 251.28). prep unchanged.

using floatx4 = __attribute__((ext_vector_type(4))) float;
using intx4   = __attribute__((ext_vector_type(4))) int;

// ---------------------------------------------------------------------------
// prep: per output-neuron o (256 blocks x 64 threads)  [unchanged]
// ---------------------------------------------------------------------------
__global__ void prep_kernel(const float* __restrict__ w_enc,
                            const float* __restrict__ b_enc,
                            const float* __restrict__ w_rnn,
                            const float* __restrict__ b_rnn,
                            double* __restrict__ Wd,
                            double* __restrict__ C0d,
                            signed char* __restrict__ Bw8)
{
    const int o = blockIdx.x;
    const int lane = threadIdx.x;   // 64 threads
    const float4 w0v = *(const float4*)(w_rnn + (size_t)o * 256 + lane * 4);
    double a0 = 0.0, a1 = 0.0, a2 = 0.0, ab = 0.0;
#pragma unroll
    for (int e = 0; e < 4; ++e) {
        const int i = lane * 4 + e;
        const double wv = (double)(((const float*)&w0v)[e]);
        a0 += wv * (double)w_enc[i * 3 + 0];
        a1 += wv * (double)w_enc[i * 3 + 1];
        a2 += wv * (double)w_enc[i * 3 + 2];
        ab += wv * (double)b_enc[i];
    }
    for (int off = 32; off > 0; off >>= 1) {
        a0 += __shfl_down(a0, off, 64);
        a1 += __shfl_down(a1, off, 64);
        a2 += __shfl_down(a2, off, 64);
        ab += __shfl_down(ab, off, 64);
    }
    if (lane == 0) {
        Wd[o * 3 + 0] = a0;
        Wd[o * 3 + 1] = a1;
        Wd[o * 3 + 2] = a2;
        C0d[o] = ab + (double)b_rnn[o];
    }
    // i8 digit planes of w1 (layer-1), 4 consecutive k per lane
    const float4 w1v = *(const float4*)(w_rnn + 65536 + (size_t)o * 256 + lane * 4);
    unsigned int pack[4] = {0u, 0u, 0u, 0u};   // pack[l]: digits for e=0..3
#pragma unroll
    for (int e = 0; e < 4; ++e) {
        float f = ((const float*)&w1v)[e];
        int q = __double2int_rn((double)f * 134217728.0);   // w * 2^27, |q| <= 2^27
        int d3 = ((q + 64) & 127) - 64;  q = (q - d3) >> 7;
        int d2 = ((q + 64) & 127) - 64;  q = (q - d2) >> 7;
        int d1 = ((q + 64) & 127) - 64;  q = (q - d1) >> 7;
        int d0 = q;                       // |d0| <= 64
        pack[0] |= ((unsigned int)(d0 & 0xFF)) << (8 * e);
        pack[1] |= ((unsigned int)(d1 & 0xFF)) << (8 * e);
        pack[2] |= ((unsigned int)(d2 & 0xFF)) << (8 * e);
        pack[3] |= ((unsigned int)(d3 & 0xFF)) << (8 * e);
    }
#pragma unroll
    for (int l = 0; l < 4; ++l)
        *(unsigned int*)(Bw8 + ((size_t)o * 4 + l) * 256 + lane * 4) = pack[l];
}

// ---------------------------------------------------------------------------
// enc R23: layer-0 scan with LDS-batched stores. Per 8-t epoch: each wave's
// lanes {0,16,32,48} write their ballot halfword to a 256-B LDS tile
// (sb[tt][4j+wid] == final row halfword order, since row byte 8j+2w ->
// halfword idx 4j+w); then 16 lanes flush 8 rows x 2 dwordx4 coalesced.
// Membrane math & output bytes BIT-IDENTICAL to the scattered version.
// ---------------------------------------------------------------------------
__global__ void enc_kernel(const float* __restrict__ inputs,
                           const double* __restrict__ Wd,
                           const double* __restrict__ C0d,
                           unsigned char* __restrict__ s0b)
{
    const int n = blockIdx.x;
    const int tidx = threadIdx.x;
    const int b = n >> 5, c = n & 31;
    __shared__ float xr[98];
    __shared__ __align__(16) unsigned short sb[8][16];   // 8 t x 32 B rows
    if (tidx < 96)       xr[tidx + 1] = inputs[((size_t)b * 96 + tidx) * 32 + c];
    else if (tidx == 96) xr[0]  = 0.0f;
    else if (tidx == 97) xr[97] = 0.0f;
    __syncthreads();
    const double W0 = Wd[tidx * 3], W1 = Wd[tidx * 3 + 1], W2 = Wd[tidx * 3 + 2];
    const double c0 = C0d[tidx];
    const int wid = tidx >> 6, lane = tidx & 63;
    const int j = lane >> 4;                 // halfword slot within ballot
    float v = 0.0f;
    for (int e = 0; e < 12; ++e) {
#pragma unroll
        for (int tt = 0; tt < 8; ++tt) {
            const int t = e * 8 + tt;
            float cur = (float)((double)xr[t] * W0 + (double)xr[t + 1] * W1 +
                                (double)xr[t + 2] * W2 + c0);
            float vv = v + (cur - v) * 0.5f;
            int sp = (vv - 1.0f) >= 0.0f;
            v = sp ? 0.0f : vv;
            unsigned long long bal = __ballot(sp);
            if ((lane & 15) == 0)
                sb[tt][4 * j + wid] = (unsigned short)(bal >> (16 * j));
        }
        __syncthreads();
        if (tidx < 16) {
            const int tt = tidx >> 1, half = tidx & 1;
            const uint4 val = *(const uint4*)&sb[tt][half * 8];
            *(uint4*)(s0b + ((size_t)(e * 8 + tt) * 2048 + n) * 32 + 16 * half) = val;
        }
        __syncthreads();
    }
}

// ---------------------------------------------------------------------------
// rnn R22 (unchanged, session best): 16x32 tile per wave, 1 wave/block,
// 1024 blocks. One bit-spread feeds TWO col-tiles (8 indep MFMA chains =
// 2 cols x 4 limbs). 3-deep step pipeline. Decision math BIT-IDENTICAL.
// C/D 16x16: M=(lane>>4)*4+reg -> out-col; N=lane&15 -> spike-row.
// ---------------------------------------------------------------------------
__global__ __launch_bounds__(64, 1) void rnn_kernel(
    const unsigned char* __restrict__ s0b,
    const signed char* __restrict__ Bw8,
    const float* __restrict__ b_rnn,
    float* __restrict__ out0,
    float* __restrict__ out1)
{
    const int lane = threadIdx.x & 63;
    const int m    = lane & 15, g = lane >> 4;

    // --- XCD-aware job mapping (bijective): 1024 jobs
    const int bidx  = blockIdx.x;            // 0..1023
    const int xcd   = bidx & 7;
    const int u     = bidx >> 3;             // 0..127
    const int rt    = 16 * xcd + (u & 15);   // 128 row-tiles
    const int cpair = u >> 4;                // 0..7 col-pairs
    const int nw    = rt * 16;
    const int o0    = cpair * 32;            // 32-col span

    // --- weight A-fragments for both col-tiles: 2 x 4 limbs x 4 chunks
    intx4 bfrag[2][4][4];
#pragma unroll
    for (int d = 0; d < 2; ++d)
#pragma unroll
        for (int l = 0; l < 4; ++l)
#pragma unroll
            for (int c = 0; c < 4; ++c)
                bfrag[d][l][c] = *(const intx4*)(Bw8
                    + ((size_t)(o0 + 16 * d + m) * 4 + l) * 256 + c * 64 + g * 16);

    // per-lane bias for out-cols (o0+16d) + 4g .. +3
    const float4 bias0 = *(const float4*)(b_rnn + 256 + o0 + g * 4);
    const float4 bias1 = *(const float4*)(b_rnn + 256 + o0 + 16 + g * 4);

    // --- store base: spike-row nw+m, col o0+4g; col-tile 1 at +16 floats ---
    float* pb = out0 + ((size_t)(nw >> 5) * 96) * 8192
                     + (size_t)((nw & 31) + m) * 256 + o0 + g * 4;

    // --- mask stream: lane reads uint2 at row*32 + 8g ---
    const unsigned char* mp = s0b + ((size_t)(nw + m)) * 32 + 8 * g;

    floatx4 v0 = {0.f, 0.f, 0.f, 0.f};
    floatx4 v1 = {0.f, 0.f, 0.f, 0.f};

    // one spread per chunk feeds both col-tiles: 8 independent chains.
    #define STEP_MFMA2(MASK, P0, P1, P2, P3, Q0, Q1, Q2, Q3)                   \
    do {                                                                       \
        unsigned int hw_[4] = { (MASK).x & 0xFFFFu, (MASK).x >> 16,            \
                                (MASK).y & 0xFFFFu, (MASK).y >> 16 };          \
        _Pragma("unroll")                                                      \
        for (int c = 0; c < 4; ++c) {                                          \
            unsigned int h_ = hw_[c];                                          \
            intx4 a_;                                                          \
            a_.x = (int)(__umul24( h_        & 0xFu, 0x00204081u) & 0x01010101u); \
            a_.y = (int)(__umul24((h_ >> 4)  & 0xFu, 0x00204081u) & 0x01010101u); \
            a_.z = (int)(__umul24((h_ >> 8)  & 0xFu, 0x00204081u) & 0x01010101u); \
            a_.w = (int)(__umul24((h_ >> 12) & 0xFu, 0x00204081u) & 0x01010101u); \
            P0 = __builtin_amdgcn_mfma_i32_16x16x64_i8(bfrag[0][0][c], a_, P0, 0, 0, 0); \
            P1 = __builtin_amdgcn_mfma_i32_16x16x64_i8(bfrag[0][1][c], a_, P1, 0, 0, 0); \
            P2 = __builtin_amdgcn_mfma_i32_16x16x64_i8(bfrag[0][2][c], a_, P2, 0, 0, 0); \
            P3 = __builtin_amdgcn_mfma_i32_16x16x64_i8(bfrag[0][3][c], a_, P3, 0, 0, 0); \
            Q0 = __builtin_amdgcn_mfma_i32_16x16x64_i8(bfrag[1][0][c], a_, Q0, 0, 0, 0); \
            Q1 = __builtin_amdgcn_mfma_i32_16x16x64_i8(bfrag[1][1][c], a_, Q1, 0, 0, 0); \
            Q2 = __builtin_amdgcn_mfma_i32_16x16x64_i8(bfrag[1][2][c], a_, Q2, 0, 0, 0); \
            Q3 = __builtin_amdgcn_mfma_i32_16x16x64_i8(bfrag[1][3][c], a_, Q3, 0, 0, 0); \
        }                                                                      \
    } while (0)

    #define MEMBRANE(ACC0, ACC1, ACC2, ACC3, VV, BIAS, SV)                     \
    do {                                                                       \
        _Pragma("unroll")                                                      \
        for (int r = 0; r < 4; ++r) {                                          \
            int a01 = (ACC0)[r] * 128 + (ACC1)[r];   /* exact, |.| < 2^22 */   \
            int a23 = (ACC2)[r] * 128 + (ACC3)[r];                             \
            float cur = fmaf((float)a01, 0x1p-13f, (float)a23 * 0x1p-27f)      \
                        + ((const float*)&(BIAS))[r];                          \
            float vv = (VV)[r];                                                \
            vv = vv + (cur - vv) * 0.5f;                                       \
            float s = ((vv - 1.0f) >= 0.0f) ? 1.0f : 0.0f;                     \
            (VV)[r] = vv * (1.0f - s);                                         \
            (SV)[r] = s;                                                       \
        }                                                                      \
    } while (0)

    // membrane + both-column stores for one step's acc set
    #define FINISH_STEP(P0, P1, P2, P3, Q0, Q1, Q2, Q3, PBOFF)                 \
    do {                                                                       \
        floatx4 sv0_, sv1_;                                                    \
        MEMBRANE(P0, P1, P2, P3, v0, bias0, sv0_);                             \
        *(floatx4*)(pb + (PBOFF)) = sv0_;                                      \
        MEMBRANE(Q0, Q1, Q2, Q3, v1, bias1, sv1_);                             \
        *(floatx4*)(pb + (PBOFF) + 16) = sv1_;                                 \
    } while (0)

    // --- mask stream: 3 steps in hand ---
    uint2 m0 = *(const uint2*)(mp);
    uint2 m1 = *(const uint2*)(mp + 65536);
    uint2 m2 = *(const uint2*)(mp + 2 * 65536);

    // groups (0..2)..(90..92); peeled (93..95)
    for (int t = 0; t < 93; t += 3) {
        uint2 p3 = *(const uint2*)(mp + (size_t)(t + 3) * 65536);
        uint2 p4 = *(const uint2*)(mp + (size_t)(t + 4) * 65536);
        uint2 p5 = *(const uint2*)(mp + (size_t)(t + 5) * 65536);

        intx4 aP0 = {0,0,0,0}, aP1 = {0,0,0,0}, aP2 = {0,0,0,0}, aP3 = {0,0,0,0};
        intx4 aQ0 = {0,0,0,0}, aQ1 = {0,0,0,0}, aQ2 = {0,0,0,0}, aQ3 = {0,0,0,0};
        intx4 bP0 = {0,0,0,0}, bP1 = {0,0,0,0}, bP2 = {0,0,0,0}, bP3 = {0,0,0,0};
        intx4 bQ0 = {0,0,0,0}, bQ1 = {0,0,0,0}, bQ2 = {0,0,0,0}, bQ3 = {0,0,0,0};
        intx4 cP0 = {0,0,0,0}, cP1 = {0,0,0,0}, cP2 = {0,0,0,0}, cP3 = {0,0,0,0};
        intx4 cQ0 = {0,0,0,0}, cQ1 = {0,0,0,0}, cQ2 = {0,0,0,0}, cQ3 = {0,0,0,0};
        STEP_MFMA2(m0, aP0, aP1, aP2, aP3, aQ0, aQ1, aQ2, aQ3);   // step t
        STEP_MFMA2(m1, bP0, bP1, bP2, bP3, bQ0, bQ1, bQ2, bQ3);   // step t+1
        STEP_MFMA2(m2, cP0, cP1, cP2, cP3, cQ0, cQ1, cQ2, cQ3);   // step t+2

        FINISH_STEP(aP0, aP1, aP2, aP3, aQ0, aQ1, aQ2, aQ3, 0);
        FINISH_STEP(bP0, bP1, bP2, bP3, bQ0, bQ1, bQ2, bQ3, 8192);
        FINISH_STEP(cP0, cP1, cP2, cP3, cQ0, cQ1, cQ2, cQ3, 16384);

        pb += 24576;
        m0 = p3; m1 = p4; m2 = p5;
    }

    // --- peeled group t = 93, 94, 95 (masks already in m0, m1, m2) ---
    {
        intx4 aP0 = {0,0,0,0}, aP1 = {0,0,0,0}, aP2 = {0,0,0,0}, aP3 = {0,0,0,0};
        intx4 aQ0 = {0,0,0,0}, aQ1 = {0,0,0,0}, aQ2 = {0,0,0,0}, aQ3 = {0,0,0,0};
        intx4 bP0 = {0,0,0,0}, bP1 = {0,0,0,0}, bP2 = {0,0,0,0}, bP3 = {0,0,0,0};
        intx4 bQ0 = {0,0,0,0}, bQ1 = {0,0,0,0}, bQ2 = {0,0,0,0}, bQ3 = {0,0,0,0};
        intx4 cP0 = {0,0,0,0}, cP1 = {0,0,0,0}, cP2 = {0,0,0,0}, cP3 = {0,0,0,0};
        intx4 cQ0 = {0,0,0,0}, cQ1 = {0,0,0,0}, cQ2 = {0,0,0,0}, cQ3 = {0,0,0,0};
        STEP_MFMA2(m0, aP0, aP1, aP2, aP3, aQ0, aQ1, aQ2, aQ3);
        STEP_MFMA2(m1, bP0, bP1, bP2, bP3, bQ0, bQ1, bQ2, bQ3);
        STEP_MFMA2(m2, cP0, cP1, cP2, cP3, cQ0, cQ1, cQ2, cQ3);

        FINISH_STEP(aP0, aP1, aP2, aP3, aQ0, aQ1, aQ2, aQ3, 0);
        FINISH_STEP(bP0, bP1, bP2, bP3, bQ0, bQ1, bQ2, bQ3, 8192);

        floatx4 sv0_, sv1_;
        MEMBRANE(cP0, cP1, cP2, cP3, v0, bias0, sv0_);
        *(floatx4*)(pb + 16384) = sv0_;
        MEMBRANE(cQ0, cQ1, cQ2, cQ3, v1, bias1, sv1_);
        *(floatx4*)(pb + 16384 + 16) = sv1_;

        float* p1 = out1 + (size_t)(nw + m) * 256 + o0 + g * 4;
        *(floatx4*)p1        = sv0_;
        *(floatx4*)(p1 + 16) = sv1_;
    }
    #undef STEP_MFMA2
    #undef MEMBRANE
    #undef FINISH_STEP
}

// ---------------------------------------------------------------------------
extern "C" void kernel_launch(void* const* d_in, const int* in_sizes, int n_in,
                              void* d_out, int out_size, void* d_ws, size_t ws_size,
                              hipStream_t stream) {
    const float* inputs = (const float*)d_in[0];   // [64,96,32]
    const float* w_enc  = (const float*)d_in[1];   // [256,1,3]
    const float* b_enc  = (const float*)d_in[2];   // [256]
    const float* w_rnn  = (const float*)d_in[3];   // [2,256,256]
    const float* b_rnn  = (const float*)d_in[4];   // [2,256]

    float* out0 = (float*)d_out;                       // [64,96,8192]
    float* out1 = out0 + (size_t)64 * 96 * 8192;       // [64,8192]

    char* ws = (char*)d_ws;
    double*      Wd  = (double*)(ws);                  //  768 doubles  [0,6144)
    double*      C0d = (double*)(ws + 6144);           //  256 doubles  [6144,8192)
    signed char* Bw8 = (signed char*)(ws + 8192);      //  256*4*256 i8 [8192,270336)
    unsigned char* s0b = (unsigned char*)(ws + 270336);// 98*65536 B spike bits (2 pad slots)

    prep_kernel<<<256, 64, 0, stream>>>(w_enc, b_enc, w_rnn, b_rnn, Wd, C0d, Bw8);
    enc_kernel<<<2048, 256, 0, stream>>>(inputs, Wd, C0d, s0b);
    rnn_kernel<<<1024, 64, 0, stream>>>(s0b, Bw8, b_rnn, out0, out1);
}